// Round 17
// baseline (1537.008 us; speedup 1.0000x reference)
//
#include <hip/hip_runtime.h>
#include <hip/hip_bf16.h>

#define B_    2
#define L_    2048
#define D_    4096
#define F_    11008
#define M_TOK (B_ * L_)          // 4096 tokens
#define BM    256
#define M_ALLOC (M_TOK + BM)     // 4352: vision [0,nv), 256-gap, language at top
#define NTM   (M_ALLOC / BM)     // 17 M-tiles
#define NT_GU (D_ / 64)          // 64 K-tiles for gate/up
#define NT_DN (F_ / 64)          // 172 K-tiles for down
#define NTILE_F (F_ / 128)       // 86 N-tiles for fused gate+up (128 cols each)
#define SPLITK_DN 4
#define LDS_GU 131072            // A 2x32KB + Bg 2x16KB + Bu 2x16KB
#define LDS_DN 131072            // A 2x32KB + B 2x32KB
#define PART_ELEMS ((size_t)M_ALLOC * D_)   // one split-K partial buffer (bf16 elems)

typedef __attribute__((ext_vector_type(8)))  __bf16 bf16x8;
typedef __attribute__((ext_vector_type(4)))  float  f32x4;
typedef __attribute__((ext_vector_type(16))) float  f32x16;
typedef unsigned short ushort_t;
typedef unsigned int   uint_t;

// ---------------------------------------------------------------- primitives

__device__ __forceinline__ void gload_lds16(const void* g, void* l) {
  __builtin_amdgcn_global_load_lds(
      (const __attribute__((address_space(1))) void*)g,
      (__attribute__((address_space(3))) void*)l, 16, 0, 0);
}

#define SCHED0()  __builtin_amdgcn_sched_barrier(0)
#define PH_BAR()  { __builtin_amdgcn_sched_barrier(0); __builtin_amdgcn_s_barrier(); __builtin_amdgcn_sched_barrier(0); }
#define LGKM(n)   { asm volatile("s_waitcnt lgkmcnt(" #n ")" ::: "memory"); __builtin_amdgcn_sched_barrier(0); }
#define VM4()     { asm volatile("s_waitcnt vmcnt(4)" ::: "memory"); __builtin_amdgcn_sched_barrier(0); }
#define VM0()     { asm volatile("s_waitcnt vmcnt(0)" ::: "memory"); __builtin_amdgcn_sched_barrier(0); }
#define PRIO1()   __builtin_amdgcn_s_setprio(1)
#define PRIO0()   __builtin_amdgcn_s_setprio(0)

__device__ __forceinline__ ushort_t f2bf(float v) {
  union { __hip_bfloat16 h; ushort_t u; } cv;
  cv.h = __float2bfloat16(v);
  return cv.u;
}

// bijective XCD swizzle (m204)
__device__ __forceinline__ int xcd_swz(int orig, int nwg) {
  const int q = nwg >> 3, r = nwg & 7, xcd = orig & 7;
  return (xcd < r ? xcd * (q + 1) : r * (q + 1) + (xcd - r) * q) + (orig >> 3);
}

// stage one 128x64 bf16 half-tile (8192 elems / 16 KB), inverse-swizzled
// source -> linear LDS. Swizzle (involution): byte ^= (row&7)<<4.
__device__ __forceinline__ void stage_half(const __hip_bfloat16* __restrict__ src, int ldE,
                                           __bf16* ldsb, int w, int lane) {
#pragma unroll
  for (int j = 0; j < 2; ++j) {
    const int ch  = (w * 2 + j) * 64 + lane;   // 16B chunk id, 0..1023
    const int row = ch >> 3;                   // 0..127
    const int cc  = (ch & 7) ^ (row & 7);      // pre-swizzled col chunk
    gload_lds16(src + (size_t)(row * ldE + cc * 8), ldsb + (w * 2 + j) * 512);
  }
}

// swizzled ds_read_b128 of one MFMA fragment from a [rows][64] bf16 region
__device__ __forceinline__ bf16x8 ldfrag(const __bf16* region, int row, int koffb) {
  const int off = ((row << 7) + koffb) ^ ((row & 7) << 4);
  return *(const bf16x8*)((const char*)region + off);
}

// 32x32x16 fragment read: row = base + (lane&31); koffb = ks*32 + (lane>>5)*16
// (lane-halves cover K=16 as 2 groups of 8 contiguous bf16 — analog of the
// verified 16x16x32 mapping where l4 groups cover K=32)

// ---------------------------------------------------------------- down K-loop
// 256x256 tile, 8 waves (2Mx4N), per-wave 128x64; r5/r13 lockstep schedule
// (measured-best for down), MFMA shape 32x32x16 (2495 TF vs 2176 for 16x16).
// acc[4][2] f32x16. vmcnt ledger unchanged: enter t with A(t+1)=4; +B(t+1)=4;
// +A(t+2)=4; VM4 retires 8 oldest. Tails drain VM0.
__device__ __forceinline__ void gemm_kloop(const __hip_bfloat16* __restrict__ Ag, const int ldA,
                                           const __hip_bfloat16* __restrict__ Bg, const int ldB,
                                           const int nt, __bf16* smem, f32x16 (&acc)[4][2],
                                           const int wm, const int wn, const int l31,
                                           const int lhi, const int w, const int lane) {
  stage_half(Ag,             ldA, smem,                w, lane);
  stage_half(Ag + 128 * ldA, ldA, smem + 8192,         w, lane);
  stage_half(Bg,             ldB, smem + 16384,        w, lane);
  stage_half(Bg + 128 * ldB, ldB, smem + 24576,        w, lane);
  if (1 < nt) {
    stage_half(Ag + 64,             ldA, smem + 32768,        w, lane);
    stage_half(Ag + 64 + 128 * ldA, ldA, smem + 32768 + 8192, w, lane);
  }
  VM4(); PH_BAR();

  for (int t = 0; t < nt; ++t) {
    __bf16* bufc = smem + (t & 1) * 32768;
    __bf16* bufn = smem + ((t + 1) & 1) * 32768;
    const __bf16* At = bufc;
    const __bf16* Bt = bufc + 16384;
    bf16x8 a0[2][4], a1[2][4], b0[4], b1[4];

    // ---- P1: a0 (m-blocks 0,1: 8 reads) + b0 (n0: 4 reads)
#pragma unroll
    for (int mb = 0; mb < 2; ++mb)
#pragma unroll
      for (int ks = 0; ks < 4; ++ks)
        a0[mb][ks] = ldfrag(At, wm * 128 + mb * 32 + l31, ks * 32 + lhi * 16);
#pragma unroll
    for (int ks = 0; ks < 4; ++ks)
      b0[ks] = ldfrag(Bt, wn * 64 + l31, ks * 32 + lhi * 16);
    if (t + 1 < nt) stage_half(Bg + (t + 1) * 64, ldB, bufn + 16384, w, lane);
    PH_BAR(); LGKM(0);
    PRIO1();
#pragma unroll
    for (int mb = 0; mb < 2; ++mb)
#pragma unroll
      for (int ks = 0; ks < 4; ++ks)
        acc[mb][0] = __builtin_amdgcn_mfma_f32_32x32x16_bf16(
            a0[mb][ks], b0[ks], acc[mb][0], 0, 0, 0);
    PRIO0();
    PH_BAR();

    // ---- P2: a1 (m-blocks 2,3: 8 reads)
#pragma unroll
    for (int mb = 0; mb < 2; ++mb)
#pragma unroll
      for (int ks = 0; ks < 4; ++ks)
        a1[mb][ks] = ldfrag(At, wm * 128 + 64 + mb * 32 + l31, ks * 32 + lhi * 16);
    if (t + 1 < nt) stage_half(Bg + (t + 1) * 64 + 128 * ldB, ldB, bufn + 24576, w, lane);
    PH_BAR(); LGKM(0);
    PRIO1();
#pragma unroll
    for (int mb = 0; mb < 2; ++mb)
#pragma unroll
      for (int ks = 0; ks < 4; ++ks)
        acc[2 + mb][0] = __builtin_amdgcn_mfma_f32_32x32x16_bf16(
            a1[mb][ks], b0[ks], acc[2 + mb][0], 0, 0, 0);
    PRIO0();
    PH_BAR();

    // ---- P3: b1 (n1: 4 reads)
#pragma unroll
    for (int ks = 0; ks < 4; ++ks)
      b1[ks] = ldfrag(Bt, wn * 64 + 32 + l31, ks * 32 + lhi * 16);
    if (t + 2 < nt) stage_half(Ag + (t + 2) * 64, ldA, bufc, w, lane);
    PH_BAR(); LGKM(0);
    PRIO1();
#pragma unroll
    for (int mb = 0; mb < 2; ++mb)
#pragma unroll
      for (int ks = 0; ks < 4; ++ks)
        acc[2 + mb][1] = __builtin_amdgcn_mfma_f32_32x32x16_bf16(
            a1[mb][ks], b1[ks], acc[2 + mb][1], 0, 0, 0);
    PRIO0();
    PH_BAR();

    // ---- P4 (register-only)
    if (t + 2 < nt) stage_half(Ag + (t + 2) * 64 + 128 * ldA, ldA, bufc + 8192, w, lane);
    PRIO1();
#pragma unroll
    for (int mb = 0; mb < 2; ++mb)
#pragma unroll
      for (int ks = 0; ks < 4; ++ks)
        acc[mb][1] = __builtin_amdgcn_mfma_f32_32x32x16_bf16(
            a0[mb][ks], b1[ks], acc[mb][1], 0, 0, 0);
    PRIO0();
    if (t + 2 < nt) { VM4(); } else { VM0(); }   // tail drain
    PH_BAR();
  }
}

// ---------------------------------------------------------------- preprocessing

__global__ void init_kernel(int* counters, int* slot2tok) {
  int i = blockIdx.x * 256 + threadIdx.x;
  if (i < 2) counters[i] = 0;
  if (i < M_ALLOC) slot2tok[i] = -1;
}

__global__ void assign_kernel(const int* __restrict__ tt, int* counters,
                              int* __restrict__ slot2tok) {
  int t = blockIdx.x * 256 + threadIdx.x;
  if (t >= M_TOK) return;
  int l = t & (L_ - 1);
  bool isv = (tt[t] == 1) && (l < L_ - 1) && (tt[t + 1] == 1);
  int slot;
  if (isv) slot = atomicAdd(&counters[0], 1);
  else     slot = M_ALLOC - 1 - atomicAdd(&counters[1], 1);
  slot2tok[slot] = t;
}

__global__ void gather_cvt(const float* __restrict__ x, const int* __restrict__ slot2tok,
                           __hip_bfloat16* __restrict__ xg) {
  const int s = blockIdx.x;
  const int t = slot2tok[s];
  __hip_bfloat16* dst = xg + (size_t)s * D_ + threadIdx.x * 16;
  union { ushort_t h[8]; uint4 v; } p0, p1;
  if (t >= 0) {
    const float4* s4 = (const float4*)(x + (size_t)t * D_ + threadIdx.x * 16);
    float4 a = s4[0], b = s4[1], c = s4[2], d = s4[3];
    float vals[16] = {a.x,a.y,a.z,a.w,b.x,b.y,b.z,b.w,c.x,c.y,c.z,c.w,d.x,d.y,d.z,d.w};
#pragma unroll
    for (int i = 0; i < 8; ++i) p0.h[i] = f2bf(vals[i]);
#pragma unroll
    for (int i = 0; i < 8; ++i) p1.h[i] = f2bf(vals[8 + i]);
  } else {
    p0.v = make_uint4(0, 0, 0, 0);
    p1.v = make_uint4(0, 0, 0, 0);
  }
  *(uint4*)dst = p0.v;
  *(uint4*)(dst + 8) = p1.v;
}

// LDS-tiled batched transpose, 6 jobs: f32 [R][C] -> bf16 [C][R].
__global__ __launch_bounds__(256) void transpose_cvt_lds6(
    const float* __restrict__ s0, const float* __restrict__ s1,
    const float* __restrict__ s2, const float* __restrict__ s3,
    const float* __restrict__ s4, const float* __restrict__ s5,
    __hip_bfloat16* __restrict__ d0, __hip_bfloat16* __restrict__ d1,
    __hip_bfloat16* __restrict__ d2, __hip_bfloat16* __restrict__ d3,
    __hip_bfloat16* __restrict__ d4, __hip_bfloat16* __restrict__ d5) {
  const float* in;
  __hip_bfloat16* out;
  switch (blockIdx.y) {
    case 0:  in = s0; out = d0; break;
    case 1:  in = s1; out = d1; break;
    case 2:  in = s2; out = d2; break;
    case 3:  in = s3; out = d3; break;
    case 4:  in = s4; out = d4; break;
    default: in = s5; out = d5; break;
  }
  const int R = (blockIdx.y < 4) ? D_ : F_;
  const int C = (blockIdx.y < 4) ? F_ : D_;
  __shared__ float tile[64][65];
  const int cb = C >> 6;
  const int c0 = (blockIdx.x % cb) * 64;
  const int r0 = (blockIdx.x / cb) * 64;
  const int tx = threadIdx.x & 63;
  const int ty = threadIdx.x >> 6;
#pragma unroll
  for (int j = 0; j < 16; ++j) {
    const int r = ty + 4 * j;
    tile[r][tx] = in[(size_t)(r0 + r) * C + c0 + tx];
  }
  __syncthreads();
  const int rr2 = (threadIdx.x & 31) * 2;
  const int cc  = threadIdx.x >> 5;
#pragma unroll
  for (int j = 0; j < 8; ++j) {
    const int c = cc + 8 * j;
    const uint_t lo = f2bf(tile[rr2][c]);
    const uint_t hi = f2bf(tile[rr2 + 1][c]);
    *(uint_t*)(out + (size_t)(c0 + c) * R + r0 + rr2) = lo | (hi << 16);
  }
}

// reduce bf16 split-K partials (slot order) and scatter to token order (f32).
__global__ __launch_bounds__(256) void reduce_scatter(
    const __hip_bfloat16* __restrict__ part, const int* __restrict__ slot2tok,
    float* __restrict__ out) {
  const int slot = blockIdx.x;
  const int tok = slot2tok[slot];
  if (tok < 0) return;
  float4* o = (float4*)(out + (size_t)tok * D_);
#pragma unroll
  for (int j = 0; j < 2; ++j) {
    const int i = j * 256 + threadIdx.x;       // uint4 index (8 bf16); D_/8 = 512
    float s[8] = {0.f, 0.f, 0.f, 0.f, 0.f, 0.f, 0.f, 0.f};
#pragma unroll
    for (int z = 0; z < SPLITK_DN; ++z) {
      const uint4 v = ((const uint4*)(part + (size_t)z * PART_ELEMS + (size_t)slot * D_))[i];
      const ushort_t* hv = (const ushort_t*)&v;
#pragma unroll
      for (int k = 0; k < 8; ++k)
        s[k] += __uint_as_float((uint_t)hv[k] << 16);
    }
    o[2 * i]     = make_float4(s[0], s[1], s[2], s[3]);
    o[2 * i + 1] = make_float4(s[4], s[5], s[6], s[7]);
  }
}

__global__ void sentinel_kernel(float* out, int n) {
  int i = blockIdx.x * 256 + threadIdx.x;
  if (i < n) out[i] = 1e30f;
}

// ---------------------------------------------------------------- GEMM 1: fused gate+up+silu
// r13-v3 counted-lgkm schedule, MFMA shape 32x32x16. Per-wave 64x64 dual acc
// (accg/accu [2][2] f32x16 = 128 AGPR, same budget). Reads per tile: af 8,
// bg 8, bu 8 (same 24 b128). G1 = af m0 (4) + all bg (8) = 12; G2 = af m1 (4);
// LGKM(4) -> m0 cluster; LGKM(0) -> m1 cluster; G3 = bu (reuse bb); PH_BAR;
// stage A(t+2); LGKM(0) -> up 16 mfma; VM4/VM0; PH_BAR. Ledger == r13.
// C/D layout (m74/m101): col = lane&31, row = (reg&3)+8*(reg>>2)+4*(lane>>5).
__global__ __launch_bounds__(512, 2) void gemm256_gateup_fused(
    const __hip_bfloat16* __restrict__ Xg,
    const __hip_bfloat16* __restrict__ WgTv, const __hip_bfloat16* __restrict__ WuTv,
    const __hip_bfloat16* __restrict__ WgTl, const __hip_bfloat16* __restrict__ WuTl,
    __hip_bfloat16* __restrict__ H, const int* __restrict__ counters) {
  extern __shared__ __bf16 smem[];
  const int tid = threadIdx.x, lane = tid & 63, w = tid >> 6;
  const int wm = w >> 1, wn = w & 1;
  const int l31 = lane & 31, lhi = lane >> 5;

  const int wg = xcd_swz(blockIdx.x, gridDim.x);
  const int mt = wg % NTM, ntile = wg / NTM;   // N-major
  const int row0 = mt * BM;
  const int ncol0 = ntile * 128;
  const int nv = counters[0];
  const bool isv = row0 < nv;
  const __hip_bfloat16* Ag   = Xg + (size_t)row0 * D_;
  const __hip_bfloat16* Bg_g = (isv ? WgTv : WgTl) + (size_t)ncol0 * D_;
  const __hip_bfloat16* Bu_g = (isv ? WuTv : WuTl) + (size_t)ncol0 * D_;

  f32x16 accg[2][2] = {};
  f32x16 accu[2][2] = {};
  const int nt = NT_GU;

  // LDS elems: A dbuf 0/16384; Bg dbuf 32768/40960; Bu dbuf 49152/57344
  stage_half(Ag,                  D_, smem,          w, lane);
  stage_half(Ag + 128 * D_,       D_, smem + 8192,   w, lane);
  stage_half(Bg_g,                D_, smem + 32768,  w, lane);
  stage_half(Bu_g,                D_, smem + 49152,  w, lane);
  stage_half(Ag + 64,             D_, smem + 16384,  w, lane);
  stage_half(Ag + 64 + 128 * D_,  D_, smem + 24576,  w, lane);
  VM4(); PH_BAR();

  for (int t = 0; t < nt; ++t) {
    const int cur = t & 1;
    const __bf16* At  = smem + cur * 16384;
    const __bf16* Bgt = smem + 32768 + cur * 8192;
    const __bf16* But = smem + 49152 + cur * 8192;
    __bf16* nxA  = smem + cur * 16384;
    __bf16* nxBg = smem + 32768 + (cur ^ 1) * 8192;
    __bf16* nxBu = smem + 49152 + (cur ^ 1) * 8192;
    bf16x8 af[2][4], bb[2][4];

    // G1 (12): af m0 (4 ks) + all bg (2n x 4 ks)
#pragma unroll
    for (int ks = 0; ks < 4; ++ks)
      af[0][ks] = ldfrag(At, wm * 64 + l31, ks * 32 + lhi * 16);
#pragma unroll
    for (int n = 0; n < 2; ++n)
#pragma unroll
      for (int ks = 0; ks < 4; ++ks)
        bb[n][ks] = ldfrag(Bgt, wn * 64 + n * 32 + l31, ks * 32 + lhi * 16);
    SCHED0();
    // G2 (4): af m1
#pragma unroll
    for (int ks = 0; ks < 4; ++ks)
      af[1][ks] = ldfrag(At, wm * 64 + 32 + l31, ks * 32 + lhi * 16);
    SCHED0();
    // stage Bg(t+1), Bu(t+1) into alt buffers (read finished in t-1)
    if (t + 1 < nt) {
      stage_half(Bg_g + (t + 1) * 64, D_, nxBg, w, lane);
      stage_half(Bu_g + (t + 1) * 64, D_, nxBu, w, lane);
    }
    SCHED0();
    LGKM(4);   // G1 retired; af m1 may still fly
    PRIO1();
#pragma unroll
    for (int n = 0; n < 2; ++n)
#pragma unroll
      for (int ks = 0; ks < 4; ++ks)
        accg[0][n] = __builtin_amdgcn_mfma_f32_32x32x16_bf16(
            af[0][ks], bb[n][ks], accg[0][n], 0, 0, 0);
    PRIO0();
    LGKM(0);   // af m1 retired -> ALL af+bg reads of this wave retired
    PRIO1();
#pragma unroll
    for (int n = 0; n < 2; ++n)
#pragma unroll
      for (int ks = 0; ks < 4; ++ks)
        accg[1][n] = __builtin_amdgcn_mfma_f32_32x32x16_bf16(
            af[1][ks], bb[n][ks], accg[1][n], 0, 0, 0);
    PRIO0();
    // G3 (8): all bu, reusing bb (bg dead). Targets Bu buffer (A-stage safe).
#pragma unroll
    for (int n = 0; n < 2; ++n)
#pragma unroll
      for (int ks = 0; ks < 4; ++ks)
        bb[n][ks] = ldfrag(But, wn * 64 + n * 32 + l31, ks * 32 + lhi * 16);
    SCHED0();
    PH_BAR();  // all af reads globally retired -> safe to overwrite A buffer
    if (t + 2 < nt) {
      stage_half(Ag + (t + 2) * 64,            D_, nxA,        w, lane);
      stage_half(Ag + (t + 2) * 64 + 128 * D_, D_, nxA + 8192, w, lane);
    }
    SCHED0();
    LGKM(0);   // bu retired
    PRIO1();
#pragma unroll
    for (int m = 0; m < 2; ++m)
#pragma unroll
      for (int n = 0; n < 2; ++n)
#pragma unroll
        for (int ks = 0; ks < 4; ++ks)
          accu[m][n] = __builtin_amdgcn_mfma_f32_32x32x16_bf16(
              af[m][ks], bb[n][ks], accu[m][n], 0, 0, 0);
    PRIO0();
    if (t + 2 < nt) { VM4(); } else { VM0(); }
    PH_BAR();
  }

  // epilogue: H = silu(g) * u, bf16.  row=(reg&3)+8*(reg>>2)+4*lhi, col=l31.
#pragma unroll
  for (int m = 0; m < 2; ++m) {
#pragma unroll
    for (int n = 0; n < 2; ++n) {
      const int colg = ncol0 + wn * 64 + n * 32 + l31;
      const int rowb = row0 + wm * 64 + m * 32 + 4 * lhi;
#pragma unroll
      for (int q = 0; q < 4; ++q)
#pragma unroll
        for (int s = 0; s < 4; ++s) {
          const int reg = q * 4 + s;
          const float g = accg[m][n][reg];
          const float u = accu[m][n][reg];
          H[(size_t)(rowb + q * 8 + s) * F_ + colg] =
              __float2bfloat16(g / (1.0f + __expf(-g)) * u);
        }
    }
  }
}

// ---------------------------------------------------------------- GEMM 2: down -> bf16 slot-order partials

__global__ __launch_bounds__(512, 2) void gemm256_down(
    const __hip_bfloat16* __restrict__ H,
    const __hip_bfloat16* __restrict__ WdTv, const __hip_bfloat16* __restrict__ WdTl,
    __hip_bfloat16* __restrict__ part, const int* __restrict__ counters) {
  extern __shared__ __bf16 smem[];
  const int tid = threadIdx.x, lane = tid & 63, w = tid >> 6;
  const int wm = w >> 2, wn = w & 3;
  const int l31 = lane & 31, lhi = lane >> 5;

  const int wg = xcd_swz(blockIdx.x, gridDim.x);
  const int mt = wg % NTM, ntt = wg / NTM;   // N-major
  const int z  = blockIdx.y;                 // split-K
  const int row0 = mt * BM;
  const int ncol0 = ntt * 256;
  const int ntz = NT_DN / SPLITK_DN;         // 43
  const int t0 = z * ntz;
  const int nv = counters[0];
  const __hip_bfloat16* Bsrc = (row0 < nv) ? WdTv : WdTl;
  const __hip_bfloat16* Ag = H + (size_t)row0 * F_ + t0 * 64;
  const __hip_bfloat16* Bg = Bsrc + (size_t)ncol0 * F_ + t0 * 64;

  f32x16 acc[4][2] = {};
  gemm_kloop(Ag, F_, Bg, F_, ntz, smem, acc, wm, wn, l31, lhi, w, lane);

  __hip_bfloat16* pz = part + (size_t)z * PART_ELEMS;
#pragma unroll
  for (int mb = 0; mb < 4; ++mb) {
#pragma unroll
    for (int nb = 0; nb < 2; ++nb) {
      const int col = ncol0 + wn * 64 + nb * 32 + l31;
      const int rowb = row0 + wm * 128 + mb * 32 + 4 * lhi;
#pragma unroll
      for (int q = 0; q < 4; ++q)
#pragma unroll
        for (int s = 0; s < 4; ++s)
          pz[(size_t)(rowb + q * 8 + s) * D_ + col] =
              __float2bfloat16(acc[mb][nb][q * 4 + s]);
    }
  }
}

// ---------------------------------------------------------------- host

extern "C" void kernel_launch(void* const* d_in, const int* in_sizes, int n_in,
                              void* d_out, int out_size, void* d_ws, size_t ws_size,
                              hipStream_t stream) {
  const float* x   = (const float*)d_in[0];
  const int*   tt  = (const int*)d_in[1];
  const float* wgv = (const float*)d_in[2];
  const float* wuv = (const float*)d_in[3];
  const float* wdv = (const float*)d_in[4];
  const float* wgl = (const float*)d_in[5];
  const float* wul = (const float*)d_in[6];
  const float* wdl = (const float*)d_in[7];
  float* out = (float*)d_out;

  size_t off = 0;
  auto nalign = [](size_t v) { return (v + 255) & ~(size_t)255; };
  const size_t o_cnt = off; off += nalign(2 * sizeof(int));
  const size_t o_s2t = off; off += nalign((size_t)M_ALLOC * sizeof(int));
  const size_t o_xg  = off; off += nalign((size_t)M_ALLOC * D_ * 2);
  const size_t o_h   = off; off += nalign((size_t)M_ALLOC * F_ * 2);
  const size_t wbytes = nalign((size_t)D_ * F_ * 2);
  const size_t o_wgv = off; off += wbytes;   // reused as bf16 split-K partials after gateup
  const size_t o_wuv = off; off += wbytes;
  const size_t o_wgl = off; off += wbytes;
  const size_t o_wul = off; off += wbytes;
  const size_t o_wdv = off; off += wbytes;
  const size_t o_wdl = off; off += wbytes;

  if (ws_size < off) {
    sentinel_kernel<<<(out_size + 255) / 256, 256, 0, stream>>>(out, out_size);
    return;
  }

  char* ws = (char*)d_ws;
  int* counters = (int*)(ws + o_cnt);
  int* slot2tok = (int*)(ws + o_s2t);
  __hip_bfloat16* Xg  = (__hip_bfloat16*)(ws + o_xg);
  __hip_bfloat16* H   = (__hip_bfloat16*)(ws + o_h);
  __hip_bfloat16* WgTv = (__hip_bfloat16*)(ws + o_wgv);
  __hip_bfloat16* WuTv = (__hip_bfloat16*)(ws + o_wuv);
  __hip_bfloat16* WgTl = (__hip_bfloat16*)(ws + o_wgl);
  __hip_bfloat16* WuTl = (__hip_bfloat16*)(ws + o_wul);
  __hip_bfloat16* WdTv = (__hip_bfloat16*)(ws + o_wdv);
  __hip_bfloat16* WdTl = (__hip_bfloat16*)(ws + o_wdl);
  __hip_bfloat16* part = (__hip_bfloat16*)(ws + o_wgv);  // aliases dead gate/up weights

  hipFuncSetAttribute((const void*)gemm256_gateup_fused,
                      hipFuncAttributeMaxDynamicSharedMemorySize, LDS_GU);
  hipFuncSetAttribute((const void*)gemm256_down,
                      hipFuncAttributeMaxDynamicSharedMemorySize, LDS_DN);

  init_kernel<<<(M_ALLOC + 255) / 256, 256, 0, stream>>>(counters, slot2tok);
  assign_kernel<<<(M_TOK + 255) / 256, 256, 0, stream>>>(tt, counters, slot2tok);
  gather_cvt<<<M_ALLOC, 256, 0, stream>>>(x, slot2tok, Xg);

  // all 6 transposes in one launch (6 independent ws buffers)
  const int tblocks = (F_ / 64) * (D_ / 64);   // 11008, same both orientations
  transpose_cvt_lds6<<<dim3(tblocks, 6), 256, 0, stream>>>(
      wgv, wuv, wgl, wul, wdv, wdl, WgTv, WuTv, WgTl, WuTl, WdTv, WdTl);

  gemm256_gateup_fused<<<dim3(NTM * NTILE_F), 512, LDS_GU, stream>>>(
      Xg, WgTv, WuTv, WgTl, WuTl, H, counters);

  gemm256_down<<<dim3(NTM * (D_ / 256), SPLITK_DN), 512, LDS_DN, stream>>>(
      H, WdTv, WdTl, part, counters);

  reduce_scatter<<<M_ALLOC, 256, 0, stream>>>(part, slot2tok, out);
}

// Round 18
// 1388.936 us; speedup vs baseline: 1.1066x; 1.1066x over previous
//
#include <hip/hip_runtime.h>
#include <hip/hip_bf16.h>

#define B_    2
#define L_    2048
#define D_    4096
#define F_    11008
#define M_TOK (B_ * L_)          // 4096 tokens
#define BM    256
#define M_ALLOC (M_TOK + BM)     // 4352: vision [0,nv), 256-gap, language at top
#define NTM   (M_ALLOC / BM)     // 17 M-tiles
#define NT_GU (D_ / 64)          // 64 K-tiles for gate/up
#define NT_DN (F_ / 64)          // 172 K-tiles for down
#define NTILE_F (F_ / 128)       // 86 N-tiles for fused gate+up (128 cols each)
#define SPLITK_DN 4
#define LDS_GU 131072            // A 2x32KB + Bg 2x16KB + Bu 2x16KB
#define LDS_DN 131072            // A 2x32KB + B 2x32KB
#define PART_ELEMS ((size_t)M_ALLOC * D_)   // one split-K partial buffer (bf16 elems)

typedef __attribute__((ext_vector_type(8))) __bf16 bf16x8;
typedef __attribute__((ext_vector_type(4))) float  f32x4;
typedef unsigned short ushort_t;
typedef unsigned int   uint_t;

// ---------------------------------------------------------------- primitives

__device__ __forceinline__ void gload_lds16(const void* g, void* l) {
  __builtin_amdgcn_global_load_lds(
      (const __attribute__((address_space(1))) void*)g,
      (__attribute__((address_space(3))) void*)l, 16, 0, 0);
}

#define SCHED0()  __builtin_amdgcn_sched_barrier(0)
#define PH_BAR()  { __builtin_amdgcn_sched_barrier(0); __builtin_amdgcn_s_barrier(); __builtin_amdgcn_sched_barrier(0); }
#define LGKM(n)   { asm volatile("s_waitcnt lgkmcnt(" #n ")" ::: "memory"); __builtin_amdgcn_sched_barrier(0); }
#define VM4()     { asm volatile("s_waitcnt vmcnt(4)" ::: "memory"); __builtin_amdgcn_sched_barrier(0); }
#define VM0()     { asm volatile("s_waitcnt vmcnt(0)" ::: "memory"); __builtin_amdgcn_sched_barrier(0); }
#define PRIO1()   __builtin_amdgcn_s_setprio(1)
#define PRIO0()   __builtin_amdgcn_s_setprio(0)

__device__ __forceinline__ ushort_t f2bf(float v) {
  union { __hip_bfloat16 h; ushort_t u; } cv;
  cv.h = __float2bfloat16(v);
  return cv.u;
}

// bijective XCD swizzle (m204)
__device__ __forceinline__ int xcd_swz(int orig, int nwg) {
  const int q = nwg >> 3, r = nwg & 7, xcd = orig & 7;
  return (xcd < r ? xcd * (q + 1) : r * (q + 1) + (xcd - r) * q) + (orig >> 3);
}

// stage one 128x64 bf16 half-tile (8192 elems / 16 KB), inverse-swizzled
// source -> linear LDS. Swizzle (involution): byte ^= (row&7)<<4.
__device__ __forceinline__ void stage_half(const __hip_bfloat16* __restrict__ src, int ldE,
                                           __bf16* ldsb, int w, int lane) {
#pragma unroll
  for (int j = 0; j < 2; ++j) {
    const int ch  = (w * 2 + j) * 64 + lane;   // 16B chunk id, 0..1023
    const int row = ch >> 3;                   // 0..127
    const int cc  = (ch & 7) ^ (row & 7);      // pre-swizzled col chunk
    gload_lds16(src + (size_t)(row * ldE + cc * 8), ldsb + (w * 2 + j) * 512);
  }
}

// swizzled ds_read_b128 of one MFMA fragment from a [rows][64] bf16 region
__device__ __forceinline__ bf16x8 ldfrag(const __bf16* region, int row, int koffb) {
  const int off = ((row << 7) + koffb) ^ ((row & 7) << 4);
  return *(const bf16x8*)((const char*)region + off);
}

__device__ __forceinline__ void mfma_q(f32x4 (&acc)[8][4], int mb, int nb,
                                       const bf16x8 (&af)[4][2], const bf16x8 (&bf)[2][2]) {
#pragma unroll
  for (int mm = 0; mm < 4; ++mm)
#pragma unroll
    for (int nn = 0; nn < 2; ++nn)
#pragma unroll
      for (int ks = 0; ks < 2; ++ks)
        acc[mb + mm][nb + nn] = __builtin_amdgcn_mfma_f32_16x16x32_bf16(
            af[mm][ks], bf[nn][ks], acc[mb + mm][nb + nn], 0, 0, 0);
}

// 256x256 tile, 8 waves (2Mx4N), per-wave 128x64. 4 phases per K-tile.
// (round-5/13 verified lockstep schedule for the down GEMM)
// NOTE r17 lesson: 16x16x32 is the REQUIRED shape here — 32x32x16 fragment
// reads (32 rows/lane-group vs 8 swizzle slots) are a structural 4-way LDS
// bank conflict (+7e7 conflicts, -12% measured).
__device__ __forceinline__ void gemm_kloop(const __hip_bfloat16* __restrict__ Ag, const int ldA,
                                           const __hip_bfloat16* __restrict__ Bg, const int ldB,
                                           const int nt, __bf16* smem, f32x4 (&acc)[8][4],
                                           const int wm, const int wn, const int l15,
                                           const int l4, const int w, const int lane) {
  stage_half(Ag,             ldA, smem,                w, lane);
  stage_half(Ag + 128 * ldA, ldA, smem + 8192,         w, lane);
  stage_half(Bg,             ldB, smem + 16384,        w, lane);
  stage_half(Bg + 128 * ldB, ldB, smem + 24576,        w, lane);
  if (1 < nt) {
    stage_half(Ag + 64,             ldA, smem + 32768,        w, lane);
    stage_half(Ag + 64 + 128 * ldA, ldA, smem + 32768 + 8192, w, lane);
  }
  VM4(); PH_BAR();

  for (int t = 0; t < nt; ++t) {
    __bf16* bufc = smem + (t & 1) * 32768;
    __bf16* bufn = smem + ((t + 1) & 1) * 32768;
    const __bf16* At = bufc;
    const __bf16* Bt = bufc + 16384;
    bf16x8 a0[4][2], a1[4][2], b0[2][2], b1[2][2];

    // ---- P1
#pragma unroll
    for (int i = 0; i < 4; ++i)
#pragma unroll
      for (int ks = 0; ks < 2; ++ks)
        a0[i][ks] = ldfrag(At, wm * 128 + i * 16 + l15, ks * 64 + l4 * 16);
#pragma unroll
    for (int n = 0; n < 2; ++n)
#pragma unroll
      for (int ks = 0; ks < 2; ++ks)
        b0[n][ks] = ldfrag(Bt, wn * 64 + n * 16 + l15, ks * 64 + l4 * 16);
    if (t + 1 < nt) stage_half(Bg + (t + 1) * 64, ldB, bufn + 16384, w, lane);
    PH_BAR(); LGKM(0);
    PRIO1(); mfma_q(acc, 0, 0, a0, b0); PRIO0();
    PH_BAR();

    // ---- P2
#pragma unroll
    for (int i = 0; i < 4; ++i)
#pragma unroll
      for (int ks = 0; ks < 2; ++ks)
        a1[i][ks] = ldfrag(At, wm * 128 + 64 + i * 16 + l15, ks * 64 + l4 * 16);
    if (t + 1 < nt) stage_half(Bg + (t + 1) * 64 + 128 * ldB, ldB, bufn + 24576, w, lane);
    PH_BAR(); LGKM(0);
    PRIO1(); mfma_q(acc, 4, 0, a1, b0); PRIO0();
    PH_BAR();

    // ---- P3
#pragma unroll
    for (int n = 0; n < 2; ++n)
#pragma unroll
      for (int ks = 0; ks < 2; ++ks)
        b1[n][ks] = ldfrag(Bt, wn * 64 + 32 + n * 16 + l15, ks * 64 + l4 * 16);
    if (t + 2 < nt) stage_half(Ag + (t + 2) * 64, ldA, bufc, w, lane);
    PH_BAR(); LGKM(0);
    PRIO1(); mfma_q(acc, 4, 2, a1, b1); PRIO0();
    PH_BAR();

    // ---- P4
    if (t + 2 < nt) stage_half(Ag + (t + 2) * 64 + 128 * ldA, ldA, bufc + 8192, w, lane);
    PRIO1(); mfma_q(acc, 0, 2, a0, b1); PRIO0();
    if (t + 2 < nt) { VM4(); } else { VM0(); }   // tail drain
    PH_BAR();
  }
}

// ---------------------------------------------------------------- preprocessing

__global__ void init_kernel(int* counters, int* slot2tok) {
  int i = blockIdx.x * 256 + threadIdx.x;
  if (i < 2) counters[i] = 0;
  if (i < M_ALLOC) slot2tok[i] = -1;
}

__global__ void assign_kernel(const int* __restrict__ tt, int* counters,
                              int* __restrict__ slot2tok) {
  int t = blockIdx.x * 256 + threadIdx.x;
  if (t >= M_TOK) return;
  int l = t & (L_ - 1);
  bool isv = (tt[t] == 1) && (l < L_ - 1) && (tt[t + 1] == 1);
  int slot;
  if (isv) slot = atomicAdd(&counters[0], 1);
  else     slot = M_ALLOC - 1 - atomicAdd(&counters[1], 1);
  slot2tok[slot] = t;
}

__global__ void gather_cvt(const float* __restrict__ x, const int* __restrict__ slot2tok,
                           __hip_bfloat16* __restrict__ xg) {
  const int s = blockIdx.x;
  const int t = slot2tok[s];
  __hip_bfloat16* dst = xg + (size_t)s * D_ + threadIdx.x * 16;
  union { ushort_t h[8]; uint4 v; } p0, p1;
  if (t >= 0) {
    const float4* s4 = (const float4*)(x + (size_t)t * D_ + threadIdx.x * 16);
    float4 a = s4[0], b = s4[1], c = s4[2], d = s4[3];
    float vals[16] = {a.x,a.y,a.z,a.w,b.x,b.y,b.z,b.w,c.x,c.y,c.z,c.w,d.x,d.y,d.z,d.w};
#pragma unroll
    for (int i = 0; i < 8; ++i) p0.h[i] = f2bf(vals[i]);
#pragma unroll
    for (int i = 0; i < 8; ++i) p1.h[i] = f2bf(vals[8 + i]);
  } else {
    p0.v = make_uint4(0, 0, 0, 0);
    p1.v = make_uint4(0, 0, 0, 0);
  }
  *(uint4*)dst = p0.v;
  *(uint4*)(dst + 8) = p1.v;
}

// LDS-tiled batched transpose, 6 jobs: f32 [R][C] -> bf16 [C][R].
__global__ __launch_bounds__(256) void transpose_cvt_lds6(
    const float* __restrict__ s0, const float* __restrict__ s1,
    const float* __restrict__ s2, const float* __restrict__ s3,
    const float* __restrict__ s4, const float* __restrict__ s5,
    __hip_bfloat16* __restrict__ d0, __hip_bfloat16* __restrict__ d1,
    __hip_bfloat16* __restrict__ d2, __hip_bfloat16* __restrict__ d3,
    __hip_bfloat16* __restrict__ d4, __hip_bfloat16* __restrict__ d5) {
  const float* in;
  __hip_bfloat16* out;
  switch (blockIdx.y) {
    case 0:  in = s0; out = d0; break;
    case 1:  in = s1; out = d1; break;
    case 2:  in = s2; out = d2; break;
    case 3:  in = s3; out = d3; break;
    case 4:  in = s4; out = d4; break;
    default: in = s5; out = d5; break;
  }
  const int R = (blockIdx.y < 4) ? D_ : F_;
  const int C = (blockIdx.y < 4) ? F_ : D_;
  __shared__ float tile[64][65];
  const int cb = C >> 6;
  const int c0 = (blockIdx.x % cb) * 64;
  const int r0 = (blockIdx.x / cb) * 64;
  const int tx = threadIdx.x & 63;
  const int ty = threadIdx.x >> 6;
#pragma unroll
  for (int j = 0; j < 16; ++j) {
    const int r = ty + 4 * j;
    tile[r][tx] = in[(size_t)(r0 + r) * C + c0 + tx];
  }
  __syncthreads();
  const int rr2 = (threadIdx.x & 31) * 2;
  const int cc  = threadIdx.x >> 5;
#pragma unroll
  for (int j = 0; j < 8; ++j) {
    const int c = cc + 8 * j;
    const uint_t lo = f2bf(tile[rr2][c]);
    const uint_t hi = f2bf(tile[rr2 + 1][c]);
    *(uint_t*)(out + (size_t)(c0 + c) * R + r0 + rr2) = lo | (hi << 16);
  }
}

// reduce bf16 split-K partials (slot order) and scatter to token order (f32).
// one block per slot row; skips gap rows. Sum in f32.
__global__ __launch_bounds__(256) void reduce_scatter(
    const __hip_bfloat16* __restrict__ part, const int* __restrict__ slot2tok,
    float* __restrict__ out) {
  const int slot = blockIdx.x;
  const int tok = slot2tok[slot];
  if (tok < 0) return;
  float4* o = (float4*)(out + (size_t)tok * D_);
#pragma unroll
  for (int j = 0; j < 2; ++j) {
    const int i = j * 256 + threadIdx.x;       // uint4 index (8 bf16); D_/8 = 512
    float s[8] = {0.f, 0.f, 0.f, 0.f, 0.f, 0.f, 0.f, 0.f};
#pragma unroll
    for (int z = 0; z < SPLITK_DN; ++z) {
      const uint4 v = ((const uint4*)(part + (size_t)z * PART_ELEMS + (size_t)slot * D_))[i];
      const ushort_t* hv = (const ushort_t*)&v;
#pragma unroll
      for (int k = 0; k < 8; ++k)
        s[k] += __uint_as_float((uint_t)hv[k] << 16);
    }
    o[2 * i]     = make_float4(s[0], s[1], s[2], s[3]);
    o[2 * i + 1] = make_float4(s[4], s[5], s[6], s[7]);
  }
}

__global__ void sentinel_kernel(float* out, int n) {
  int i = blockIdx.x * 256 + threadIdx.x;
  if (i < n) out[i] = 1e30f;
}

// ---------------------------------------------------------------- GEMM 1: fused gate+up+silu
// v3 counted-lgkm schedule (r13-verified, ~679 us, MfmaUtil 54).
__global__ __launch_bounds__(512, 2) void gemm256_gateup_fused(
    const __hip_bfloat16* __restrict__ Xg,
    const __hip_bfloat16* __restrict__ WgTv, const __hip_bfloat16* __restrict__ WuTv,
    const __hip_bfloat16* __restrict__ WgTl, const __hip_bfloat16* __restrict__ WuTl,
    __hip_bfloat16* __restrict__ H, const int* __restrict__ counters) {
  extern __shared__ __bf16 smem[];
  const int tid = threadIdx.x, lane = tid & 63, w = tid >> 6;
  const int wm = w >> 1, wn = w & 1;
  const int l15 = lane & 15, l4 = lane >> 4;

  const int wg = xcd_swz(blockIdx.x, gridDim.x);
  const int mt = wg % NTM, ntile = wg / NTM;   // N-major
  const int row0 = mt * BM;
  const int ncol0 = ntile * 128;
  const int nv = counters[0];
  const bool isv = row0 < nv;
  const __hip_bfloat16* Ag   = Xg + (size_t)row0 * D_;
  const __hip_bfloat16* Bg_g = (isv ? WgTv : WgTl) + (size_t)ncol0 * D_;
  const __hip_bfloat16* Bu_g = (isv ? WuTv : WuTl) + (size_t)ncol0 * D_;

  f32x4 accg[4][4] = {};
  f32x4 accu[4][4] = {};
  const int nt = NT_GU;

  // LDS elems: A dbuf 0/16384; Bg dbuf 32768/40960; Bu dbuf 49152/57344
  stage_half(Ag,                  D_, smem,          w, lane);
  stage_half(Ag + 128 * D_,       D_, smem + 8192,   w, lane);
  stage_half(Bg_g,                D_, smem + 32768,  w, lane);
  stage_half(Bu_g,                D_, smem + 49152,  w, lane);
  stage_half(Ag + 64,             D_, smem + 16384,  w, lane);
  stage_half(Ag + 64 + 128 * D_,  D_, smem + 24576,  w, lane);
  VM4(); PH_BAR();

  for (int t = 0; t < nt; ++t) {
    const int cur = t & 1;
    const __bf16* At  = smem + cur * 16384;
    const __bf16* Bgt = smem + 32768 + cur * 8192;
    const __bf16* But = smem + 49152 + cur * 8192;
    __bf16* nxA  = smem + cur * 16384;
    __bf16* nxBg = smem + 32768 + (cur ^ 1) * 8192;
    __bf16* nxBu = smem + 49152 + (cur ^ 1) * 8192;
    bf16x8 af[4][2], bb[4][2];

    // G1 (12): af m01 + all bg
#pragma unroll
    for (int m = 0; m < 2; ++m)
#pragma unroll
      for (int ks = 0; ks < 2; ++ks)
        af[m][ks] = ldfrag(At, wm * 64 + m * 16 + l15, ks * 64 + l4 * 16);
#pragma unroll
    for (int n = 0; n < 4; ++n)
#pragma unroll
      for (int ks = 0; ks < 2; ++ks)
        bb[n][ks] = ldfrag(Bgt, wn * 64 + n * 16 + l15, ks * 64 + l4 * 16);
    SCHED0();
    // G2 (4): af m23
#pragma unroll
    for (int m = 2; m < 4; ++m)
#pragma unroll
      for (int ks = 0; ks < 2; ++ks)
        af[m][ks] = ldfrag(At, wm * 64 + m * 16 + l15, ks * 64 + l4 * 16);
    SCHED0();
    // stage Bg(t+1), Bu(t+1) into alt buffers (read finished in t-1)
    if (t + 1 < nt) {
      stage_half(Bg_g + (t + 1) * 64, D_, nxBg, w, lane);
      stage_half(Bu_g + (t + 1) * 64, D_, nxBu, w, lane);
    }
    SCHED0();
    LGKM(4);   // G1 retired; af m23 may still fly
    PRIO1();
#pragma unroll
    for (int m = 0; m < 2; ++m)
#pragma unroll
      for (int n = 0; n < 4; ++n)
#pragma unroll
        for (int ks = 0; ks < 2; ++ks)
          accg[m][n] = __builtin_amdgcn_mfma_f32_16x16x32_bf16(
              af[m][ks], bb[n][ks], accg[m][n], 0, 0, 0);
    PRIO0();
    LGKM(0);   // af m23 retired -> ALL af+bg reads of this wave retired
    PRIO1();
#pragma unroll
    for (int m = 2; m < 4; ++m)
#pragma unroll
      for (int n = 0; n < 4; ++n)
#pragma unroll
        for (int ks = 0; ks < 2; ++ks)
          accg[m][n] = __builtin_amdgcn_mfma_f32_16x16x32_bf16(
              af[m][ks], bb[n][ks], accg[m][n], 0, 0, 0);
    PRIO0();
    // G3 (8): all bu, reusing bb (bg dead). Targets Bu buffer (A-stage safe).
#pragma unroll
    for (int n = 0; n < 4; ++n)
#pragma unroll
      for (int ks = 0; ks < 2; ++ks)
        bb[n][ks] = ldfrag(But, wn * 64 + n * 16 + l15, ks * 64 + l4 * 16);
    SCHED0();
    PH_BAR();  // all af reads globally retired -> safe to overwrite A buffer
    if (t + 2 < nt) {
      stage_half(Ag + (t + 2) * 64,            D_, nxA,        w, lane);
      stage_half(Ag + (t + 2) * 64 + 128 * D_, D_, nxA + 8192, w, lane);
    }
    SCHED0();
    LGKM(0);   // bu retired
    PRIO1();
#pragma unroll
    for (int m = 0; m < 4; ++m)
#pragma unroll
      for (int n = 0; n < 4; ++n)
#pragma unroll
        for (int ks = 0; ks < 2; ++ks)
          accu[m][n] = __builtin_amdgcn_mfma_f32_16x16x32_bf16(
              af[m][ks], bb[n][ks], accu[m][n], 0, 0, 0);
    PRIO0();
    if (t + 2 < nt) { VM4(); } else { VM0(); }
    PH_BAR();
  }

  // epilogue: H = silu(g) * u, bf16
#pragma unroll
  for (int m = 0; m < 4; ++m) {
    const int grow = row0 + wm * 64 + m * 16 + l4 * 4;
#pragma unroll
    for (int rr = 0; rr < 4; ++rr) {
      __hip_bfloat16* orow = H + (size_t)(grow + rr) * F_ + ncol0 + wn * 64 + l15;
#pragma unroll
      for (int n = 0; n < 4; ++n) {
        const float g = accg[m][n][rr];
        const float u = accu[m][n][rr];
        orow[n * 16] = __float2bfloat16(g / (1.0f + __expf(-g)) * u);
      }
    }
  }
}

// ---------------------------------------------------------------- GEMM 2: down -> bf16 slot-order partials

__global__ __launch_bounds__(512, 2) void gemm256_down(
    const __hip_bfloat16* __restrict__ H,
    const __hip_bfloat16* __restrict__ WdTv, const __hip_bfloat16* __restrict__ WdTl,
    __hip_bfloat16* __restrict__ part, const int* __restrict__ counters) {
  extern __shared__ __bf16 smem[];
  const int tid = threadIdx.x, lane = tid & 63, w = tid >> 6;
  const int wm = w >> 2, wn = w & 3;
  const int l15 = lane & 15, l4 = lane >> 4;

  const int wg = xcd_swz(blockIdx.x, gridDim.x);
  const int mt = wg % NTM, ntt = wg / NTM;   // N-major
  const int z  = blockIdx.y;                 // split-K
  const int row0 = mt * BM;
  const int ncol0 = ntt * 256;
  const int ntz = NT_DN / SPLITK_DN;         // 43
  const int t0 = z * ntz;
  const int nv = counters[0];
  const __hip_bfloat16* Bsrc = (row0 < nv) ? WdTv : WdTl;
  const __hip_bfloat16* Ag = H + (size_t)row0 * F_ + t0 * 64;
  const __hip_bfloat16* Bg = Bsrc + (size_t)ncol0 * F_ + t0 * 64;

  f32x4 acc[8][4] = {};
  gemm_kloop(Ag, F_, Bg, F_, ntz, smem, acc, wm, wn, l15, l4, w, lane);

  __hip_bfloat16* pz = part + (size_t)z * PART_ELEMS;
#pragma unroll
  for (int m = 0; m < 8; ++m) {
    const int slot = row0 + wm * 128 + m * 16 + l4 * 4;
#pragma unroll
    for (int rr = 0; rr < 4; ++rr) {
      __hip_bfloat16* prow = pz + (size_t)(slot + rr) * D_ + ncol0 + wn * 64 + l15;
#pragma unroll
      for (int n = 0; n < 4; ++n)
        prow[n * 16] = __float2bfloat16(acc[m][n][rr]);
    }
  }
}

// ---------------------------------------------------------------- host

extern "C" void kernel_launch(void* const* d_in, const int* in_sizes, int n_in,
                              void* d_out, int out_size, void* d_ws, size_t ws_size,
                              hipStream_t stream) {
  const float* x   = (const float*)d_in[0];
  const int*   tt  = (const int*)d_in[1];
  const float* wgv = (const float*)d_in[2];
  const float* wuv = (const float*)d_in[3];
  const float* wdv = (const float*)d_in[4];
  const float* wgl = (const float*)d_in[5];
  const float* wul = (const float*)d_in[6];
  const float* wdl = (const float*)d_in[7];
  float* out = (float*)d_out;

  size_t off = 0;
  auto nalign = [](size_t v) { return (v + 255) & ~(size_t)255; };
  const size_t o_cnt = off; off += nalign(2 * sizeof(int));
  const size_t o_s2t = off; off += nalign((size_t)M_ALLOC * sizeof(int));
  const size_t o_xg  = off; off += nalign((size_t)M_ALLOC * D_ * 2);
  const size_t o_h   = off; off += nalign((size_t)M_ALLOC * F_ * 2);
  const size_t wbytes = nalign((size_t)D_ * F_ * 2);
  const size_t o_wgv = off; off += wbytes;   // reused as bf16 split-K partials after gateup
  const size_t o_wuv = off; off += wbytes;
  const size_t o_wgl = off; off += wbytes;
  const size_t o_wul = off; off += wbytes;
  const size_t o_wdv = off; off += wbytes;
  const size_t o_wdl = off; off += wbytes;

  if (ws_size < off) {
    sentinel_kernel<<<(out_size + 255) / 256, 256, 0, stream>>>(out, out_size);
    return;
  }

  char* ws = (char*)d_ws;
  int* counters = (int*)(ws + o_cnt);
  int* slot2tok = (int*)(ws + o_s2t);
  __hip_bfloat16* Xg  = (__hip_bfloat16*)(ws + o_xg);
  __hip_bfloat16* H   = (__hip_bfloat16*)(ws + o_h);
  __hip_bfloat16* WgTv = (__hip_bfloat16*)(ws + o_wgv);
  __hip_bfloat16* WuTv = (__hip_bfloat16*)(ws + o_wuv);
  __hip_bfloat16* WgTl = (__hip_bfloat16*)(ws + o_wgl);
  __hip_bfloat16* WuTl = (__hip_bfloat16*)(ws + o_wul);
  __hip_bfloat16* WdTv = (__hip_bfloat16*)(ws + o_wdv);
  __hip_bfloat16* WdTl = (__hip_bfloat16*)(ws + o_wdl);
  __hip_bfloat16* part = (__hip_bfloat16*)(ws + o_wgv);  // aliases dead gate/up weights

  hipFuncSetAttribute((const void*)gemm256_gateup_fused,
                      hipFuncAttributeMaxDynamicSharedMemorySize, LDS_GU);
  hipFuncSetAttribute((const void*)gemm256_down,
                      hipFuncAttributeMaxDynamicSharedMemorySize, LDS_DN);

  init_kernel<<<(M_ALLOC + 255) / 256, 256, 0, stream>>>(counters, slot2tok);
  assign_kernel<<<(M_TOK + 255) / 256, 256, 0, stream>>>(tt, counters, slot2tok);
  gather_cvt<<<M_ALLOC, 256, 0, stream>>>(x, slot2tok, Xg);

  // all 6 transposes in one launch (6 independent ws buffers)
  const int tblocks = (F_ / 64) * (D_ / 64);   // 11008, same both orientations
  transpose_cvt_lds6<<<dim3(tblocks, 6), 256, 0, stream>>>(
      wgv, wuv, wgl, wul, wdv, wdl, WgTv, WuTv, WgTl, WuTl, WdTv, WdTl);

  gemm256_gateup_fused<<<dim3(NTM * NTILE_F), 512, LDS_GU, stream>>>(
      Xg, WgTv, WuTv, WgTl, WuTl, H, counters);

  gemm256_down<<<dim3(NTM * (D_ / 256), SPLITK_DN), 512, LDS_DN, stream>>>(
      H, WdTv, WdTl, part, counters);

  reduce_scatter<<<M_ALLOC, 256, 0, stream>>>(part, slot2tok, out);
}